// Round 18
// baseline (380.039 us; speedup 1.0000x reference)
//
#include <hip/hip_runtime.h>
#include <hip/hip_fp16.h>

#define NN 100000
#define NE 1600000
#define N64 (NN * 64)
#define NB 1563                       // buckets = dst>>6 (ceil(100000/64))
#define CAP2 1280                     // bucket capacity (mean ~1024, +8 sigma)
#define MLP1_BLKS 391                 // mlp1 role: block covers 256 nodes x 4 quarters
#define BKT_BLKS 196                  // 196 * 1024 * 8 >= NE

typedef __attribute__((ext_vector_type(8))) _Float16 f16x8;
typedef __attribute__((ext_vector_type(4))) float fx4;

// ---- workspace layout (dword offsets) ----
#define W1D_OFF 0
#define W1S_OFF 448
#define WB1F_OFF 9216                 // f16 Wb frags layer1: 2048 dwords
#define WB2F_OFF 11264                // layer2: 2048 dwords
#define W2C_OFF 13312                 // combined f16 W2a frags (Wd||Ws): 4096 dwords
#define GCUR_OFF 17408                // bucket cursors [NB]
#define A_OFF   32768                 // packed f16: 32 dwords/node
#define B_OFF   (A_OFF + N64 / 2)
#define G1_OFF  (B_OFF + N64 / 2)     // layer-1 agg out, f16: 32 dwords/node
#define G2_OFF  (G1_OFF + N64 / 2)
#define P1_OFF  (G2_OFF + N64 / 2)    // int2[NB*CAP2] bucket staging

union FragH { unsigned u[4]; f16x8 f; };

static __device__ __forceinline__ unsigned pack_h2(float f0, float f1) {
    __half h0 = __float2half_rn(f0), h1 = __float2half_rn(f1);
    unsigned short u0 = *(unsigned short*)&h0, u1 = *(unsigned short*)&h1;
    return (unsigned)u0 | ((unsigned)u1 << 16);
}

// Prep: zero bucket cursors, precombine W1a, build f16 Wb frags + combined
// layer-2 node-MLP weight frags (Wd = top-bottom || Ws = bottom).
__global__ __launch_bounds__(256) void prep_all(
    const float* __restrict__ W1a, const float* __restrict__ W1b,
    const float* __restrict__ W2a, const float* __restrict__ W2b,
    float* __restrict__ ws, int* __restrict__ gcur)
{
    int t = blockIdx.x * 256 + threadIdx.x;
    if (t < NB) gcur[t] = 0;
    if (t < 448) {
        float top = W1a[t], bot = W1a[448 + t];
        ws[W1D_OFF + t] = top - bot;
        ws[W1S_OFF + t] = bot;
    }
    if (t < 1024) {
        int layer = t >> 9;
        int r = t & 511;
        int ks = (r >> 8) & 1, nt = (r >> 6) & 3, lane = r & 63;
        const float* Wb = layer ? W2b : W1b;
        int* out = (int*)(ws + (layer ? WB2F_OFF : WB1F_OFF));
        int quad = lane >> 4, c = lane & 15, n = nt * 16 + c;
        unsigned dw[4];
#pragma unroll
        for (int d = 0; d < 4; ++d) {
            int k0 = quad * 8 + d * 2 + 32 * ks;
            dw[d] = pack_h2(Wb[k0 * 64 + n], Wb[(k0 + 1) * 64 + n]);
        }
        ((int4*)out)[r] = make_int4((int)dw[0], (int)dw[1], (int)dw[2], (int)dw[3]);
    }
    if (t >= 1024 && t < 2048) {
        int r = t - 1024;                       // ks*512 + nt*64 + lane
        int ks = (r >> 9) & 1, nt8 = (r >> 6) & 7, lane = r & 63;
        int quad = lane >> 4, c = lane & 15;
        int ncol = nt8 * 16 + c;                // 0..127
        int* out = (int*)(ws + W2C_OFF);
        unsigned dw[4];
#pragma unroll
        for (int d = 0; d < 4; ++d) {
            unsigned v[2];
#pragma unroll
            for (int e = 0; e < 2; ++e) {
                int k = quad * 8 + d * 2 + e + 32 * ks;
                float w = (ncol < 64)
                    ? (W2a[k * 64 + ncol] - W2a[(64 + k) * 64 + ncol])
                    : W2a[(64 + k) * 64 + (ncol - 64)];
                __half h = __float2half_rn(w);
                v[e] = *(unsigned short*)&h;
            }
            dw[d] = (v[1] << 16) | v[0];
        }
        ((int4*)out)[r] = make_int4((int)dw[0], (int)dw[1], (int)dw[2], (int)dw[3]);
    }
}

// Fused (1024-thread blocks): [0,MLP1_BLKS) = node-MLP1 (t>>8 selects output
// quarter, block covers 256 nodes); rest = bucket multisplit (dst>>6, NB=1563).
__global__ __launch_bounds__(1024) void fused_mlp1_bucket(
    const float* __restrict__ x, const float* __restrict__ Wd,
    const float* __restrict__ Ws, const float* __restrict__ ba,
    unsigned* __restrict__ A16, unsigned* __restrict__ Bu,
    const int* __restrict__ src, const int* __restrict__ dst,
    int* __restrict__ gcur, int2* __restrict__ p1)
{
    __shared__ int cnt[NB];
    __shared__ int cur[NB];
    const int t = threadIdx.x;

    if (blockIdx.x < MLP1_BLKS) {
        const int q = t >> 8;
        const int i = blockIdx.x * 256 + (t & 255);
        if (i >= NN) return;
        float xv[7];
#pragma unroll
        for (int k = 0; k < 7; ++k) xv[k] = x[i * 7 + k];
        uint4* pa = (uint4*)(A16 + (size_t)i * 32 + q * 8);
        uint4* pb = (uint4*)(Bu + (size_t)i * 32 + q * 8);
        float acc[16];
#pragma unroll
        for (int c = 0; c < 16; ++c) acc[c] = ba[q * 16 + c];
#pragma unroll
        for (int k = 0; k < 7; ++k)
#pragma unroll
            for (int c = 0; c < 16; ++c)
                acc[c] = fmaf(xv[k], Wd[k * 64 + q * 16 + c], acc[c]);
        pa[0] = make_uint4(pack_h2(acc[0], acc[1]),  pack_h2(acc[2], acc[3]),
                           pack_h2(acc[4], acc[5]),  pack_h2(acc[6], acc[7]));
        pa[1] = make_uint4(pack_h2(acc[8], acc[9]),  pack_h2(acc[10], acc[11]),
                           pack_h2(acc[12], acc[13]), pack_h2(acc[14], acc[15]));
#pragma unroll
        for (int c = 0; c < 16; ++c) acc[c] = 0.0f;
#pragma unroll
        for (int k = 0; k < 7; ++k)
#pragma unroll
            for (int c = 0; c < 16; ++c)
                acc[c] = fmaf(xv[k], Ws[k * 64 + q * 16 + c], acc[c]);
        pb[0] = make_uint4(pack_h2(acc[0], acc[1]),  pack_h2(acc[2], acc[3]),
                           pack_h2(acc[4], acc[5]),  pack_h2(acc[6], acc[7]));
        pb[1] = make_uint4(pack_h2(acc[8], acc[9]),  pack_h2(acc[10], acc[11]),
                           pack_h2(acc[12], acc[13]), pack_h2(acc[14], acc[15]));
        return;
    }

    // ---- bucket role ----
    const int bb = blockIdx.x - MLP1_BLKS;
    const int e0 = (bb * 1024 + t) * 8;
    const bool ok = (e0 < NE);                   // NE % 8 == 0
    for (int i = t; i < NB; i += 1024) cnt[i] = 0;
    int ss[8], dd[8], bk[8];
    if (ok) {
        int4 d0 = ((const int4*)(dst + e0))[0];
        int4 d1 = ((const int4*)(dst + e0))[1];
        int4 s0 = ((const int4*)(src + e0))[0];
        int4 s1 = ((const int4*)(src + e0))[1];
        dd[0]=d0.x; dd[1]=d0.y; dd[2]=d0.z; dd[3]=d0.w;
        dd[4]=d1.x; dd[5]=d1.y; dd[6]=d1.z; dd[7]=d1.w;
        ss[0]=s0.x; ss[1]=s0.y; ss[2]=s0.z; ss[3]=s0.w;
        ss[4]=s1.x; ss[5]=s1.y; ss[6]=s1.z; ss[7]=s1.w;
    }
    __syncthreads();
    if (ok) {
#pragma unroll
        for (int j = 0; j < 8; ++j) { bk[j] = dd[j] >> 6; atomicAdd(&cnt[bk[j]], 1); }
    }
    __syncthreads();
    for (int i = t; i < NB; i += 1024)
        cur[i] = atomicAdd(&gcur[i], cnt[i]);    // reserve block ranges
    __syncthreads();
    if (ok) {
#pragma unroll
        for (int j = 0; j < 8; ++j) {
            int pos = atomicAdd(&cur[bk[j]], 1);
            p1[(size_t)bk[j] * CAP2 + pos] = make_int2(ss[j], dd[j]);
        }
    }
}

// Edge layer, bucket-resident (R15 structure): one block per 64-node bucket.
// fp32 agg in LDS (stride 66); edges unsorted from p1; wave = 32 edges; f16
// MFMA; epilogue = ds atomicMax (non-neg floats order as uints). Index loads
// prefetched one iteration ahead. Tail slots clamp to last edge (idempotent
// under max). __launch_bounds__(256,6): 6 blocks/CU (VGPR cap 84 >= the 56
// this kernel needs; LDS 6x16.9KB=101KB) — occupancy is what this kernel
// responds to (R15 vs R16/R17 evidence), not manual pipelining.
__global__ __launch_bounds__(256, 6) void edge_layer_bucket(
    const unsigned* __restrict__ A16, const unsigned* __restrict__ Bu,
    const int2* __restrict__ p1, const int* __restrict__ gcnt,
    const int* __restrict__ wbf, const float* __restrict__ bb,
    unsigned* __restrict__ G16)
{
    __shared__ unsigned agg[64 * 66];            // 16,896 B
    const int tid = threadIdx.x;
    const int wv = tid >> 6, lane = tid & 63;
    const int quad = lane >> 4, c15 = lane & 15;
    const int b = blockIdx.x;
    const int size = gcnt[b];
    const int szm1 = size - 1;
    const int2* bp = p1 + (size_t)b * CAP2;

    for (int i = tid; i < 64 * 66; i += 256) agg[i] = 0u;

    FragH wf[2][4];                              // persistent across iterations
#pragma unroll
    for (int ks = 0; ks < 2; ++ks)
#pragma unroll
        for (int nt = 0; nt < 4; ++nt) {
            int4 v = ((const int4*)wbf)[(ks * 4 + nt) * 64 + lane];
            wf[ks][nt].u[0] = (unsigned)v.x; wf[ks][nt].u[1] = (unsigned)v.y;
            wf[ks][nt].u[2] = (unsigned)v.z; wf[ks][nt].u[3] = (unsigned)v.w;
        }
    float bbv[4];
#pragma unroll
    for (int nt = 0; nt < 4; ++nt) bbv[nt] = bb[nt * 16 + c15];
    __syncthreads();

    const int niter = (size + 127) >> 7;
    // preload iteration-0 indices
    int2 ed = make_int2(0, 0), eb0 = ed, eb1 = ed;
    if (niter > 0) {
        int base = wv * 32;
        ed  = bp[min(base + (lane & 31), szm1)];
        eb0 = bp[min(base + c15, szm1)];
        eb1 = bp[min(base + 16 + c15, szm1)];
    }

    for (int it = 0; it < niter; ++it) {
        const int2 ced = ed, ceb0 = eb0, ceb1 = eb1;
        if (it + 1 < niter) {                    // prefetch next indices
            int nb2 = (it + 1) * 128 + wv * 32;
            ed  = bp[min(nb2 + (lane & 31), szm1)];
            eb0 = bp[min(nb2 + c15, szm1)];
            eb1 = bp[min(nb2 + 16 + c15, szm1)];
        }
        const int dloc = ced.y & 63;             // dst - b*64

        const unsigned* pa0 = A16 + (size_t)ceb0.y * 32 + quad * 4;
        const unsigned* pb0 = Bu  + (size_t)ceb0.x * 32 + quad * 4;
        const unsigned* pa1 = A16 + (size_t)ceb1.y * 32 + quad * 4;
        const unsigned* pb1 = Bu  + (size_t)ceb1.x * 32 + quad * 4;

        uint4 ga[2][2], gb[2][2];
#pragma unroll
        for (int ks = 0; ks < 2; ++ks) {
            ga[0][ks] = ((const uint4*)(pa0 + ks * 16))[0];
            gb[0][ks] = ((const uint4*)(pb0 + ks * 16))[0];
            ga[1][ks] = ((const uint4*)(pa1 + ks * 16))[0];
            gb[1][ks] = ((const uint4*)(pb1 + ks * 16))[0];
        }

        FragH tf[2][2];
#pragma unroll
        for (int mt = 0; mt < 2; ++mt)
#pragma unroll
            for (int ks = 0; ks < 2; ++ks) {
                FragH ua, ub;
                ua.u[0] = ga[mt][ks].x; ua.u[1] = ga[mt][ks].y;
                ua.u[2] = ga[mt][ks].z; ua.u[3] = ga[mt][ks].w;
                ub.u[0] = gb[mt][ks].x; ub.u[1] = gb[mt][ks].y;
                ub.u[2] = gb[mt][ks].z; ub.u[3] = gb[mt][ks].w;
                f16x8 s = ua.f + ub.f;
                tf[mt][ks].f = __builtin_elementwise_max(s, (f16x8)(_Float16)0.0f);
            }

        fx4 acc[2][4];
#pragma unroll
        for (int mt = 0; mt < 2; ++mt)
#pragma unroll
            for (int nt = 0; nt < 4; ++nt)
                acc[mt][nt] = (fx4){0.f, 0.f, 0.f, 0.f};
#pragma unroll
        for (int ks = 0; ks < 2; ++ks)
#pragma unroll
            for (int mt = 0; mt < 2; ++mt)
#pragma unroll
                for (int nt = 0; nt < 4; ++nt)
                    acc[mt][nt] = __builtin_amdgcn_mfma_f32_16x16x32_f16(
                        tf[mt][ks].f, wf[ks][nt].f, acc[mt][nt], 0, 0, 0);

        // epilogue: per value (edge 16mt+4q+r, ch 16nt+c15) -> ds atomic max
#pragma unroll
        for (int mt = 0; mt < 2; ++mt)
#pragma unroll
            for (int r = 0; r < 4; ++r) {
                int dl = __builtin_amdgcn_ds_bpermute(
                    (16 * mt + 4 * quad + r) * 4, dloc);
                int abase = dl * 66 + c15;
#pragma unroll
                for (int nt = 0; nt < 4; ++nt) {
                    float h = fmaxf(acc[mt][nt][r] + bbv[nt], 0.f);
                    atomicMax(&agg[abase + nt * 16], __float_as_uint(h));
                }
            }
    }
    __syncthreads();

    // writeout: 4 threads per node, 16 ch each, f16 packed
    const int nl = tid >> 2, part = tid & 3;
    const int node = b * 64 + nl;
    if (node < NN) {
        unsigned* out = G16 + (size_t)node * 32 + part * 8;
#pragma unroll
        for (int j = 0; j < 8; ++j) {
            float f0 = __uint_as_float(agg[nl * 66 + part * 16 + 2 * j]);
            float f1 = __uint_as_float(agg[nl * 66 + part * 16 + 2 * j + 1]);
            out[j] = pack_h2(f0, f1);
        }
    }
}

// Node MLP layer 2 as MFMA GEMM over f16 g: [NN x 64] @ [64 x 128] (Wd || Ws).
__global__ __launch_bounds__(256, 3) void node_mlp2_mfma(
    const unsigned* __restrict__ g16, const int* __restrict__ wcf,
    const float* __restrict__ ba2,
    unsigned* __restrict__ A16, unsigned* __restrict__ Bu)
{
    const int tid = threadIdx.x;
    const int wv = tid >> 6, lane = tid & 63;
    const int quad = lane >> 4, c15 = lane & 15;
    const int nbase = (blockIdx.x * 4 + wv) * 32;
    if (nbase >= NN) return;                     // 3125 full waves exactly

    FragH tf[2][2];
#pragma unroll
    for (int mt = 0; mt < 2; ++mt) {
        const unsigned* pr = g16 + (size_t)(nbase + mt * 16 + c15) * 32 + quad * 4;
#pragma unroll
        for (int ks = 0; ks < 2; ++ks) {
            uint4 v = ((const uint4*)(pr + ks * 16))[0];
            tf[mt][ks].u[0] = v.x; tf[mt][ks].u[1] = v.y;
            tf[mt][ks].u[2] = v.z; tf[mt][ks].u[3] = v.w;
        }
    }

    fx4 acc[2][8];
#pragma unroll
    for (int mt = 0; mt < 2; ++mt)
#pragma unroll
        for (int nt = 0; nt < 8; ++nt)
            acc[mt][nt] = (fx4){0.f, 0.f, 0.f, 0.f};

#pragma unroll
    for (int ks = 0; ks < 2; ++ks) {
        FragH wf[8];
#pragma unroll
        for (int nt = 0; nt < 8; ++nt) {
            int4 v = ((const int4*)wcf)[(ks * 8 + nt) * 64 + lane];
            wf[nt].u[0] = (unsigned)v.x; wf[nt].u[1] = (unsigned)v.y;
            wf[nt].u[2] = (unsigned)v.z; wf[nt].u[3] = (unsigned)v.w;
        }
#pragma unroll
        for (int mt = 0; mt < 2; ++mt)
#pragma unroll
            for (int nt = 0; nt < 8; ++nt)
                acc[mt][nt] = __builtin_amdgcn_mfma_f32_16x16x32_f16(
                    tf[mt][ks].f, wf[nt].f, acc[mt][nt], 0, 0, 0);
    }

    __half* Ah = (__half*)A16;
    __half* Bh = (__half*)Bu;
#pragma unroll
    for (int nt = 0; nt < 8; ++nt) {
        float bbv = (nt < 4) ? ba2[nt * 16 + c15] : 0.f;
        __half* out = (nt < 4) ? Ah : Bh;
        int ch = (nt & 3) * 16 + c15;
#pragma unroll
        for (int mt = 0; mt < 2; ++mt)
#pragma unroll
            for (int r = 0; r < 4; ++r) {
                int node = nbase + mt * 16 + quad * 4 + r;
                out[(size_t)node * 64 + ch] = __float2half_rn(acc[mt][nt][r] + bbv);
            }
    }
}

// out[i] = h2[i,:] @ Wl + bl, h2 stored f16
__global__ __launch_bounds__(256) void final_linear(
    const unsigned* __restrict__ g2, const float* __restrict__ Wl,
    const float* __restrict__ bl, float* __restrict__ out)
{
    int i = blockIdx.x * 256 + threadIdx.x;
    if (i >= NN) return;
    const uint4* row = (const uint4*)(g2 + (size_t)i * 32);
    float acc = bl[0];
#pragma unroll
    for (int q = 0; q < 8; ++q) {
        uint4 v = row[q];
        unsigned u[4] = { v.x, v.y, v.z, v.w };
#pragma unroll
        for (int d = 0; d < 4; ++d) {
            float2 f = __half22float2(*(const __half2*)&u[d]);
            acc = fmaf(f.x, Wl[q * 8 + d * 2], acc);
            acc = fmaf(f.y, Wl[q * 8 + d * 2 + 1], acc);
        }
    }
    out[i] = acc;
}

extern "C" void kernel_launch(void* const* d_in, const int* in_sizes, int n_in,
                              void* d_out, int out_size, void* d_ws, size_t ws_size,
                              hipStream_t stream)
{
    const float* x   = (const float*)d_in[0];
    const int*   ei  = (const int*)d_in[1];
    const float* W1a = (const float*)d_in[2];
    const float* b1a = (const float*)d_in[3];
    const float* W1b = (const float*)d_in[4];
    const float* b1b = (const float*)d_in[5];
    const float* W2a = (const float*)d_in[6];
    const float* b2a = (const float*)d_in[7];
    const float* W2b = (const float*)d_in[8];
    const float* b2b = (const float*)d_in[9];
    const float* Wl  = (const float*)d_in[10];
    const float* bl  = (const float*)d_in[11];

    const int* src = ei;
    const int* dst = ei + NE;

    float* ws = (float*)d_ws;
    unsigned* A16 = (unsigned*)(ws + A_OFF);
    unsigned* Bu  = (unsigned*)(ws + B_OFF);
    unsigned* G1  = (unsigned*)(ws + G1_OFF);
    unsigned* G2  = (unsigned*)(ws + G2_OFF);
    int*  gcur  = (int*)(ws + GCUR_OFF);
    int2* p1    = (int2*)(ws + P1_OFF);

    prep_all<<<16, 256, 0, stream>>>(W1a, W1b, W2a, W2b, ws, gcur);

    fused_mlp1_bucket<<<MLP1_BLKS + BKT_BLKS, 1024, 0, stream>>>(
        x, ws + W1D_OFF, ws + W1S_OFF, b1a, A16, Bu, src, dst, gcur, p1);

    edge_layer_bucket<<<NB, 256, 0, stream>>>(A16, Bu, p1, gcur,
                                              (const int*)(ws + WB1F_OFF), b1b, G1);

    node_mlp2_mfma<<<782, 256, 0, stream>>>(G1, (const int*)(ws + W2C_OFF),
                                            b2a, A16, Bu);

    edge_layer_bucket<<<NB, 256, 0, stream>>>(A16, Bu, p1, gcur,
                                              (const int*)(ws + WB2F_OFF), b2b, G2);

    final_linear<<<391, 256, 0, stream>>>(G2, Wl, bl, (float*)d_out);
}

// Round 19
// 260.645 us; speedup vs baseline: 1.4581x; 1.4581x over previous
//
#include <hip/hip_runtime.h>
#include <hip/hip_fp16.h>

#define NN 100000
#define NE 1600000
#define N64 (NN * 64)
#define NB 1563                       // buckets = dst>>6 (ceil(100000/64))
#define CAP2 1280                     // bucket capacity (mean ~1024, +8 sigma)
#define MLP1_BLKS 391                 // mlp1 role: block covers 256 nodes x 4 quarters
#define BKT_BLKS 196                  // 196 * 1024 * 8 >= NE

typedef __attribute__((ext_vector_type(8))) _Float16 f16x8;
typedef __attribute__((ext_vector_type(4))) float fx4;

// ---- workspace layout (dword offsets) ----
#define W1D_OFF 0
#define W1S_OFF 448
#define WB1F_OFF 9216                 // f16 Wb frags layer1: 2048 dwords
#define WB2F_OFF 11264                // layer2: 2048 dwords
#define W2C_OFF 13312                 // combined f16 W2a frags (Wd||Ws): 4096 dwords
#define GCUR_OFF 17408                // bucket cursors [NB]
#define A_OFF   32768                 // packed f16: 32 dwords/node
#define B_OFF   (A_OFF + N64 / 2)
#define G1_OFF  (B_OFF + N64 / 2)     // layer-1 agg out, f16: 32 dwords/node
#define G2_OFF  (G1_OFF + N64 / 2)
#define P1_OFF  (G2_OFF + N64 / 2)    // int2[NB*CAP2] bucket staging

union FragH { unsigned u[4]; f16x8 f; };

static __device__ __forceinline__ unsigned pack_h2(float f0, float f1) {
    __half h0 = __float2half_rn(f0), h1 = __float2half_rn(f1);
    unsigned short u0 = *(unsigned short*)&h0, u1 = *(unsigned short*)&h1;
    return (unsigned)u0 | ((unsigned)u1 << 16);
}

// Prep: zero bucket cursors, precombine W1a, build f16 Wb frags + combined
// layer-2 node-MLP weight frags (Wd = top-bottom || Ws = bottom).
__global__ __launch_bounds__(256) void prep_all(
    const float* __restrict__ W1a, const float* __restrict__ W1b,
    const float* __restrict__ W2a, const float* __restrict__ W2b,
    float* __restrict__ ws, int* __restrict__ gcur)
{
    int t = blockIdx.x * 256 + threadIdx.x;
    if (t < NB) gcur[t] = 0;
    if (t < 448) {
        float top = W1a[t], bot = W1a[448 + t];
        ws[W1D_OFF + t] = top - bot;
        ws[W1S_OFF + t] = bot;
    }
    if (t < 1024) {
        int layer = t >> 9;
        int r = t & 511;
        int ks = (r >> 8) & 1, nt = (r >> 6) & 3, lane = r & 63;
        const float* Wb = layer ? W2b : W1b;
        int* out = (int*)(ws + (layer ? WB2F_OFF : WB1F_OFF));
        int quad = lane >> 4, c = lane & 15, n = nt * 16 + c;
        unsigned dw[4];
#pragma unroll
        for (int d = 0; d < 4; ++d) {
            int k0 = quad * 8 + d * 2 + 32 * ks;
            dw[d] = pack_h2(Wb[k0 * 64 + n], Wb[(k0 + 1) * 64 + n]);
        }
        ((int4*)out)[r] = make_int4((int)dw[0], (int)dw[1], (int)dw[2], (int)dw[3]);
    }
    if (t >= 1024 && t < 2048) {
        int r = t - 1024;                       // ks*512 + nt*64 + lane
        int ks = (r >> 9) & 1, nt8 = (r >> 6) & 7, lane = r & 63;
        int quad = lane >> 4, c = lane & 15;
        int ncol = nt8 * 16 + c;                // 0..127
        int* out = (int*)(ws + W2C_OFF);
        unsigned dw[4];
#pragma unroll
        for (int d = 0; d < 4; ++d) {
            unsigned v[2];
#pragma unroll
            for (int e = 0; e < 2; ++e) {
                int k = quad * 8 + d * 2 + e + 32 * ks;
                float w = (ncol < 64)
                    ? (W2a[k * 64 + ncol] - W2a[(64 + k) * 64 + ncol])
                    : W2a[(64 + k) * 64 + (ncol - 64)];
                __half h = __float2half_rn(w);
                v[e] = *(unsigned short*)&h;
            }
            dw[d] = (v[1] << 16) | v[0];
        }
        ((int4*)out)[r] = make_int4((int)dw[0], (int)dw[1], (int)dw[2], (int)dw[3]);
    }
}

// Fused (1024-thread blocks): [0,MLP1_BLKS) = node-MLP1 (t>>8 selects output
// quarter, block covers 256 nodes); rest = bucket multisplit (dst>>6, NB=1563).
__global__ __launch_bounds__(1024) void fused_mlp1_bucket(
    const float* __restrict__ x, const float* __restrict__ Wd,
    const float* __restrict__ Ws, const float* __restrict__ ba,
    unsigned* __restrict__ A16, unsigned* __restrict__ Bu,
    const int* __restrict__ src, const int* __restrict__ dst,
    int* __restrict__ gcur, int2* __restrict__ p1)
{
    __shared__ int cnt[NB];
    __shared__ int cur[NB];
    const int t = threadIdx.x;

    if (blockIdx.x < MLP1_BLKS) {
        const int q = t >> 8;
        const int i = blockIdx.x * 256 + (t & 255);
        if (i >= NN) return;
        float xv[7];
#pragma unroll
        for (int k = 0; k < 7; ++k) xv[k] = x[i * 7 + k];
        uint4* pa = (uint4*)(A16 + (size_t)i * 32 + q * 8);
        uint4* pb = (uint4*)(Bu + (size_t)i * 32 + q * 8);
        float acc[16];
#pragma unroll
        for (int c = 0; c < 16; ++c) acc[c] = ba[q * 16 + c];
#pragma unroll
        for (int k = 0; k < 7; ++k)
#pragma unroll
            for (int c = 0; c < 16; ++c)
                acc[c] = fmaf(xv[k], Wd[k * 64 + q * 16 + c], acc[c]);
        pa[0] = make_uint4(pack_h2(acc[0], acc[1]),  pack_h2(acc[2], acc[3]),
                           pack_h2(acc[4], acc[5]),  pack_h2(acc[6], acc[7]));
        pa[1] = make_uint4(pack_h2(acc[8], acc[9]),  pack_h2(acc[10], acc[11]),
                           pack_h2(acc[12], acc[13]), pack_h2(acc[14], acc[15]));
#pragma unroll
        for (int c = 0; c < 16; ++c) acc[c] = 0.0f;
#pragma unroll
        for (int k = 0; k < 7; ++k)
#pragma unroll
            for (int c = 0; c < 16; ++c)
                acc[c] = fmaf(xv[k], Ws[k * 64 + q * 16 + c], acc[c]);
        pb[0] = make_uint4(pack_h2(acc[0], acc[1]),  pack_h2(acc[2], acc[3]),
                           pack_h2(acc[4], acc[5]),  pack_h2(acc[6], acc[7]));
        pb[1] = make_uint4(pack_h2(acc[8], acc[9]),  pack_h2(acc[10], acc[11]),
                           pack_h2(acc[12], acc[13]), pack_h2(acc[14], acc[15]));
        return;
    }

    // ---- bucket role ----
    const int bb = blockIdx.x - MLP1_BLKS;
    const int e0 = (bb * 1024 + t) * 8;
    const bool ok = (e0 < NE);                   // NE % 8 == 0
    for (int i = t; i < NB; i += 1024) cnt[i] = 0;
    int ss[8], dd[8], bk[8];
    if (ok) {
        int4 d0 = ((const int4*)(dst + e0))[0];
        int4 d1 = ((const int4*)(dst + e0))[1];
        int4 s0 = ((const int4*)(src + e0))[0];
        int4 s1 = ((const int4*)(src + e0))[1];
        dd[0]=d0.x; dd[1]=d0.y; dd[2]=d0.z; dd[3]=d0.w;
        dd[4]=d1.x; dd[5]=d1.y; dd[6]=d1.z; dd[7]=d1.w;
        ss[0]=s0.x; ss[1]=s0.y; ss[2]=s0.z; ss[3]=s0.w;
        ss[4]=s1.x; ss[5]=s1.y; ss[6]=s1.z; ss[7]=s1.w;
    }
    __syncthreads();
    if (ok) {
#pragma unroll
        for (int j = 0; j < 8; ++j) { bk[j] = dd[j] >> 6; atomicAdd(&cnt[bk[j]], 1); }
    }
    __syncthreads();
    for (int i = t; i < NB; i += 1024)
        cur[i] = atomicAdd(&gcur[i], cnt[i]);    // reserve block ranges
    __syncthreads();
    if (ok) {
#pragma unroll
        for (int j = 0; j < 8; ++j) {
            int pos = atomicAdd(&cur[bk[j]], 1);
            p1[(size_t)bk[j] * CAP2 + pos] = make_int2(ss[j], dd[j]);
        }
    }
}

// Edge layer, bucket-resident (R15 structure): one block per 64-node bucket.
// fp32 agg in LDS (stride 66); edges unsorted from p1; wave = 32 edges; f16
// MFMA; epilogue = ds atomicMax (non-neg floats order as uints). Index loads
// prefetched one iteration ahead. Tail slots clamp to last edge (idempotent
// under max). __launch_bounds__(256,5): VGPR cap ~96 >= the ~56 this kernel
// allocates (no spill), 5 blocks/CU (LDS 5x16.9KB=84.5KB). R15(4blk)=68.9us,
// R18(6blk)=spilled at 40-VGPR cap; 5 is the untested middle point.
__global__ __launch_bounds__(256, 5) void edge_layer_bucket(
    const unsigned* __restrict__ A16, const unsigned* __restrict__ Bu,
    const int2* __restrict__ p1, const int* __restrict__ gcnt,
    const int* __restrict__ wbf, const float* __restrict__ bb,
    unsigned* __restrict__ G16)
{
    __shared__ unsigned agg[64 * 66];            // 16,896 B
    const int tid = threadIdx.x;
    const int wv = tid >> 6, lane = tid & 63;
    const int quad = lane >> 4, c15 = lane & 15;
    const int b = blockIdx.x;
    const int size = gcnt[b];
    const int szm1 = size - 1;
    const int2* bp = p1 + (size_t)b * CAP2;

    for (int i = tid; i < 64 * 66; i += 256) agg[i] = 0u;

    FragH wf[2][4];                              // persistent across iterations
#pragma unroll
    for (int ks = 0; ks < 2; ++ks)
#pragma unroll
        for (int nt = 0; nt < 4; ++nt) {
            int4 v = ((const int4*)wbf)[(ks * 4 + nt) * 64 + lane];
            wf[ks][nt].u[0] = (unsigned)v.x; wf[ks][nt].u[1] = (unsigned)v.y;
            wf[ks][nt].u[2] = (unsigned)v.z; wf[ks][nt].u[3] = (unsigned)v.w;
        }
    float bbv[4];
#pragma unroll
    for (int nt = 0; nt < 4; ++nt) bbv[nt] = bb[nt * 16 + c15];
    __syncthreads();

    const int niter = (size + 127) >> 7;
    // preload iteration-0 indices
    int2 ed = make_int2(0, 0), eb0 = ed, eb1 = ed;
    if (niter > 0) {
        int base = wv * 32;
        ed  = bp[min(base + (lane & 31), szm1)];
        eb0 = bp[min(base + c15, szm1)];
        eb1 = bp[min(base + 16 + c15, szm1)];
    }

    for (int it = 0; it < niter; ++it) {
        const int2 ced = ed, ceb0 = eb0, ceb1 = eb1;
        if (it + 1 < niter) {                    // prefetch next indices
            int nb2 = (it + 1) * 128 + wv * 32;
            ed  = bp[min(nb2 + (lane & 31), szm1)];
            eb0 = bp[min(nb2 + c15, szm1)];
            eb1 = bp[min(nb2 + 16 + c15, szm1)];
        }
        const int dloc = ced.y & 63;             // dst - b*64

        const unsigned* pa0 = A16 + (size_t)ceb0.y * 32 + quad * 4;
        const unsigned* pb0 = Bu  + (size_t)ceb0.x * 32 + quad * 4;
        const unsigned* pa1 = A16 + (size_t)ceb1.y * 32 + quad * 4;
        const unsigned* pb1 = Bu  + (size_t)ceb1.x * 32 + quad * 4;

        uint4 ga[2][2], gb[2][2];
#pragma unroll
        for (int ks = 0; ks < 2; ++ks) {
            ga[0][ks] = ((const uint4*)(pa0 + ks * 16))[0];
            gb[0][ks] = ((const uint4*)(pb0 + ks * 16))[0];
            ga[1][ks] = ((const uint4*)(pa1 + ks * 16))[0];
            gb[1][ks] = ((const uint4*)(pb1 + ks * 16))[0];
        }

        FragH tf[2][2];
#pragma unroll
        for (int mt = 0; mt < 2; ++mt)
#pragma unroll
            for (int ks = 0; ks < 2; ++ks) {
                FragH ua, ub;
                ua.u[0] = ga[mt][ks].x; ua.u[1] = ga[mt][ks].y;
                ua.u[2] = ga[mt][ks].z; ua.u[3] = ga[mt][ks].w;
                ub.u[0] = gb[mt][ks].x; ub.u[1] = gb[mt][ks].y;
                ub.u[2] = gb[mt][ks].z; ub.u[3] = gb[mt][ks].w;
                f16x8 s = ua.f + ub.f;
                tf[mt][ks].f = __builtin_elementwise_max(s, (f16x8)(_Float16)0.0f);
            }

        fx4 acc[2][4];
#pragma unroll
        for (int mt = 0; mt < 2; ++mt)
#pragma unroll
            for (int nt = 0; nt < 4; ++nt)
                acc[mt][nt] = (fx4){0.f, 0.f, 0.f, 0.f};
#pragma unroll
        for (int ks = 0; ks < 2; ++ks)
#pragma unroll
            for (int mt = 0; mt < 2; ++mt)
#pragma unroll
                for (int nt = 0; nt < 4; ++nt)
                    acc[mt][nt] = __builtin_amdgcn_mfma_f32_16x16x32_f16(
                        tf[mt][ks].f, wf[ks][nt].f, acc[mt][nt], 0, 0, 0);

        // epilogue: per value (edge 16mt+4q+r, ch 16nt+c15) -> ds atomic max
#pragma unroll
        for (int mt = 0; mt < 2; ++mt)
#pragma unroll
            for (int r = 0; r < 4; ++r) {
                int dl = __builtin_amdgcn_ds_bpermute(
                    (16 * mt + 4 * quad + r) * 4, dloc);
                int abase = dl * 66 + c15;
#pragma unroll
                for (int nt = 0; nt < 4; ++nt) {
                    float h = fmaxf(acc[mt][nt][r] + bbv[nt], 0.f);
                    atomicMax(&agg[abase + nt * 16], __float_as_uint(h));
                }
            }
    }
    __syncthreads();

    // writeout: 4 threads per node, 16 ch each, f16 packed
    const int nl = tid >> 2, part = tid & 3;
    const int node = b * 64 + nl;
    if (node < NN) {
        unsigned* out = G16 + (size_t)node * 32 + part * 8;
#pragma unroll
        for (int j = 0; j < 8; ++j) {
            float f0 = __uint_as_float(agg[nl * 66 + part * 16 + 2 * j]);
            float f1 = __uint_as_float(agg[nl * 66 + part * 16 + 2 * j + 1]);
            out[j] = pack_h2(f0, f1);
        }
    }
}

// Node MLP layer 2 as MFMA GEMM over f16 g: [NN x 64] @ [64 x 128] (Wd || Ws).
__global__ __launch_bounds__(256, 3) void node_mlp2_mfma(
    const unsigned* __restrict__ g16, const int* __restrict__ wcf,
    const float* __restrict__ ba2,
    unsigned* __restrict__ A16, unsigned* __restrict__ Bu)
{
    const int tid = threadIdx.x;
    const int wv = tid >> 6, lane = tid & 63;
    const int quad = lane >> 4, c15 = lane & 15;
    const int nbase = (blockIdx.x * 4 + wv) * 32;
    if (nbase >= NN) return;                     // 3125 full waves exactly

    FragH tf[2][2];
#pragma unroll
    for (int mt = 0; mt < 2; ++mt) {
        const unsigned* pr = g16 + (size_t)(nbase + mt * 16 + c15) * 32 + quad * 4;
#pragma unroll
        for (int ks = 0; ks < 2; ++ks) {
            uint4 v = ((const uint4*)(pr + ks * 16))[0];
            tf[mt][ks].u[0] = v.x; tf[mt][ks].u[1] = v.y;
            tf[mt][ks].u[2] = v.z; tf[mt][ks].u[3] = v.w;
        }
    }

    fx4 acc[2][8];
#pragma unroll
    for (int mt = 0; mt < 2; ++mt)
#pragma unroll
        for (int nt = 0; nt < 8; ++nt)
            acc[mt][nt] = (fx4){0.f, 0.f, 0.f, 0.f};

#pragma unroll
    for (int ks = 0; ks < 2; ++ks) {
        FragH wf[8];
#pragma unroll
        for (int nt = 0; nt < 8; ++nt) {
            int4 v = ((const int4*)wcf)[(ks * 8 + nt) * 64 + lane];
            wf[nt].u[0] = (unsigned)v.x; wf[nt].u[1] = (unsigned)v.y;
            wf[nt].u[2] = (unsigned)v.z; wf[nt].u[3] = (unsigned)v.w;
        }
#pragma unroll
        for (int mt = 0; mt < 2; ++mt)
#pragma unroll
            for (int nt = 0; nt < 8; ++nt)
                acc[mt][nt] = __builtin_amdgcn_mfma_f32_16x16x32_f16(
                    tf[mt][ks].f, wf[nt].f, acc[mt][nt], 0, 0, 0);
    }

    __half* Ah = (__half*)A16;
    __half* Bh = (__half*)Bu;
#pragma unroll
    for (int nt = 0; nt < 8; ++nt) {
        float bbv = (nt < 4) ? ba2[nt * 16 + c15] : 0.f;
        __half* out = (nt < 4) ? Ah : Bh;
        int ch = (nt & 3) * 16 + c15;
#pragma unroll
        for (int mt = 0; mt < 2; ++mt)
#pragma unroll
            for (int r = 0; r < 4; ++r) {
                int node = nbase + mt * 16 + quad * 4 + r;
                out[(size_t)node * 64 + ch] = __float2half_rn(acc[mt][nt][r] + bbv);
            }
    }
}

// out[i] = h2[i,:] @ Wl + bl, h2 stored f16
__global__ __launch_bounds__(256) void final_linear(
    const unsigned* __restrict__ g2, const float* __restrict__ Wl,
    const float* __restrict__ bl, float* __restrict__ out)
{
    int i = blockIdx.x * 256 + threadIdx.x;
    if (i >= NN) return;
    const uint4* row = (const uint4*)(g2 + (size_t)i * 32);
    float acc = bl[0];
#pragma unroll
    for (int q = 0; q < 8; ++q) {
        uint4 v = row[q];
        unsigned u[4] = { v.x, v.y, v.z, v.w };
#pragma unroll
        for (int d = 0; d < 4; ++d) {
            float2 f = __half22float2(*(const __half2*)&u[d]);
            acc = fmaf(f.x, Wl[q * 8 + d * 2], acc);
            acc = fmaf(f.y, Wl[q * 8 + d * 2 + 1], acc);
        }
    }
    out[i] = acc;
}

extern "C" void kernel_launch(void* const* d_in, const int* in_sizes, int n_in,
                              void* d_out, int out_size, void* d_ws, size_t ws_size,
                              hipStream_t stream)
{
    const float* x   = (const float*)d_in[0];
    const int*   ei  = (const int*)d_in[1];
    const float* W1a = (const float*)d_in[2];
    const float* b1a = (const float*)d_in[3];
    const float* W1b = (const float*)d_in[4];
    const float* b1b = (const float*)d_in[5];
    const float* W2a = (const float*)d_in[6];
    const float* b2a = (const float*)d_in[7];
    const float* W2b = (const float*)d_in[8];
    const float* b2b = (const float*)d_in[9];
    const float* Wl  = (const float*)d_in[10];
    const float* bl  = (const float*)d_in[11];

    const int* src = ei;
    const int* dst = ei + NE;

    float* ws = (float*)d_ws;
    unsigned* A16 = (unsigned*)(ws + A_OFF);
    unsigned* Bu  = (unsigned*)(ws + B_OFF);
    unsigned* G1  = (unsigned*)(ws + G1_OFF);
    unsigned* G2  = (unsigned*)(ws + G2_OFF);
    int*  gcur  = (int*)(ws + GCUR_OFF);
    int2* p1    = (int2*)(ws + P1_OFF);

    prep_all<<<16, 256, 0, stream>>>(W1a, W1b, W2a, W2b, ws, gcur);

    fused_mlp1_bucket<<<MLP1_BLKS + BKT_BLKS, 1024, 0, stream>>>(
        x, ws + W1D_OFF, ws + W1S_OFF, b1a, A16, Bu, src, dst, gcur, p1);

    edge_layer_bucket<<<NB, 256, 0, stream>>>(A16, Bu, p1, gcur,
                                              (const int*)(ws + WB1F_OFF), b1b, G1);

    node_mlp2_mfma<<<782, 256, 0, stream>>>(G1, (const int*)(ws + W2C_OFF),
                                            b2a, A16, Bu);

    edge_layer_bucket<<<NB, 256, 0, stream>>>(A16, Bu, p1, gcur,
                                              (const int*)(ws + WB2F_OFF), b2b, G2);

    final_linear<<<391, 256, 0, stream>>>(G2, Wl, bl, (float*)d_out);
}